// Round 10
// baseline (254.173 us; speedup 1.0000x reference)
//
#include <hip/hip_runtime.h>
#include <hip/hip_bf16.h>

// PinSageConv on MI355X — round 16 (resubmit after infra failure; unchanged).
// qgemm v14 = v13 (async f32 staging, clean read path: 800K conflicts) with
//   ONE parameter change: 32-row tiles -> 32 KB LDS -> 5 blocks/CU (v13's
//   sole failure was 64 KB -> 2 blocks/CU, Occ 18.5%). Grid 3125 = exact,
//   clamps removed. acc 2x4, VGPR ~90. B-stream cost doubles but B is a
//   128 KB L2-resident buffer (~12 µs of 34 TB/s L2, overlapped).
// aggk v3 (bf16 aggB out) + fgemm v3 (bf16 kb>=4 A-path) + fused L2-norm:
//   r15-verified, unchanged.
// Workspace: q_fp8[100000][256] @0 (25.6MB) | aggB bf16 @25.6MB (10.24MB)
//            | QwB bf16 @46,080,000 | WwB bf16 @46,211,072.

#define M_TOTAL 100000
#define N_NODES 20000
#define T_NB    50
#define IN_F    256
#define HID_F   256
#define OUT_F   256
#define KCAT    512

typedef __bf16 bf16x8 __attribute__((ext_vector_type(8)));
typedef float  floatx4 __attribute__((ext_vector_type(4)));
typedef float  v2f     __attribute__((ext_vector_type(2)));

__device__ __forceinline__ unsigned short f2bf(float f) {
    unsigned int u = __float_as_uint(f);
    u += 0x7fffu + ((u >> 16) & 1u);          // RTNE
    return (unsigned short)(u >> 16);
}
__device__ __forceinline__ void gload16(const void* g, void* l) {
    __builtin_amdgcn_global_load_lds(
        (const __attribute__((address_space(1))) unsigned int*)g,
        (__attribute__((address_space(3))) unsigned int*)l, 16, 0, 0);
}
__device__ __forceinline__ bf16x8 cvt_frag(float4 a, float4 b) {
    bf16x8 r;
    r[0] = (__bf16)a.x; r[1] = (__bf16)a.y; r[2] = (__bf16)a.z; r[3] = (__bf16)a.w;
    r[4] = (__bf16)b.x; r[5] = (__bf16)b.y; r[6] = (__bf16)b.z; r[7] = (__bf16)b.w;
    return r;
}

// ---------------------------------------------------------------------------
// Kernel 0: convert Qw (65536 f32) and Ww (131072 f32) to bf16.
// ---------------------------------------------------------------------------
__global__ __launch_bounds__(256)
void wcvt(const float* __restrict__ Qw, const float* __restrict__ Ww,
          unsigned short* __restrict__ QwB, unsigned short* __restrict__ WwB) {
    const int e = (blockIdx.x * 256 + threadIdx.x) * 4;
    float4 v;
    unsigned short* dst;
    if (e < 65536) { v = *(const float4*)(Qw + e);           dst = QwB + e; }
    else           { v = *(const float4*)(Ww + (e - 65536)); dst = WwB + (e - 65536); }
    ushort4 s;
    s.x = f2bf(v.x); s.y = f2bf(v.y); s.z = f2bf(v.z); s.w = f2bf(v.w);
    *(ushort4*)dst = s;
}

// ---------------------------------------------------------------------------
// Kernel 1: q = fp8(relu(h @ Qw.T + Qb)).  M=100000 N=256(full) K=256.
// 32x256 block, 4 waves (wave 32x64). A: async f32 into 32KB LDS, 16B-chunk
// XOR swizzle c^(r&15) applied to the SOURCE address (linear LDS dest; read
// side applies the same XOR — v13-verified clean at 800K conflicts).
// B-frags streamed from L2-resident QwB, 2-deep register dbuf. Epilogue:
// v8 pattern on a 32-row tile (per-wave 2KB fp8 quadrant -> uint4 stores).
// Grid 3125 = 100000/32 exact, no edge clamps.
// ---------------------------------------------------------------------------
__global__ __launch_bounds__(256)
void qgemm(const float* __restrict__ h, const unsigned short* __restrict__ QwB,
           const float* __restrict__ Qb, unsigned char* __restrict__ q) {
    __shared__ float ldsA[32 * 256];   // 32 KB f32; reused as fp8 epi tile

    const int tid  = threadIdx.x;
    const int row0 = blockIdx.x * 32;
    const int lane = tid & 63;
    const int wv   = tid >> 6;
    const int wc   = wv << 6;              // wave's 64-col (n) slice
    const int quad = lane >> 4;
    const int fr   = lane & 15;

    // --- Stage A async: 2048 chunks (32 rows x 64x16B), 8/thread.
#pragma unroll
    for (int i = 0; i < 8; ++i) {
        const int g = tid + i * 256;
        const int r = g >> 6;
        const int c = g & 63;
        gload16(h + (size_t)(row0 + r) * IN_F + ((c ^ (r & 15)) << 2), (char*)ldsA + g * 16);
    }

    // bias + B k0 preload issue while staging is in flight.
    float bias[4];
#pragma unroll
    for (int nt = 0; nt < 4; ++nt) bias[nt] = Qb[wc + nt * 16 + fr];

    const unsigned short* bp = QwB + (size_t)(wc + fr) * IN_F + quad * 8;
    bf16x8 bvp[2][4];
#pragma unroll
    for (int nt = 0; nt < 4; ++nt)
        bvp[0][nt] = *(const bf16x8*)(bp + nt * 16 * IN_F);

    floatx4 acc[2][4];
#pragma unroll
    for (int i = 0; i < 2; ++i)
#pragma unroll
        for (int j = 0; j < 4; ++j)
            acc[i][j] = (floatx4){0.f, 0.f, 0.f, 0.f};

    __syncthreads();                       // drains vmcnt: A tile resident

#pragma unroll
    for (int kb = 0; kb < 8; ++kb) {       // K=256, 32/step — no barriers
        const int cur = kb & 1;
        if (kb < 7) {
#pragma unroll
            for (int nt = 0; nt < 4; ++nt)
                bvp[cur ^ 1][nt] = *(const bf16x8*)(bp + nt * 16 * IN_F + (kb + 1) * 32);
        }
        bf16x8 av[2];
#pragma unroll
        for (int mt = 0; mt < 2; ++mt) {
            const int r  = mt * 16 + fr;
            const int c0 = kb * 8 + quad * 2;        // f32 16B-chunk index
            const float4 p0 = *(const float4*)(ldsA + r * 256 + ((c0 ^ fr) << 2));
            const float4 p1 = *(const float4*)(ldsA + r * 256 + (((c0 + 1) ^ fr) << 2));
            av[mt] = cvt_frag(p0, p1);
        }
#pragma unroll
        for (int mt = 0; mt < 2; ++mt)
#pragma unroll
            for (int nt = 0; nt < 4; ++nt)
                acc[mt][nt] = __builtin_amdgcn_mfma_f32_16x16x32_bf16(av[mt], bvp[cur][nt], acc[mt][nt], 0, 0, 0);
    }

    // --- Epilogue: all waves done reading ldsA, reuse as fp8 tile.
    __syncthreads();
    unsigned char* const epi = (unsigned char*)ldsA + wv * 2048;   // 32r x 64c
#pragma unroll
    for (int mt = 0; mt < 2; ++mt)
#pragma unroll
        for (int nt = 0; nt < 4; ++nt)
#pragma unroll
            for (int r = 0; r < 4; ++r) {
                float v = acc[mt][nt][r] + bias[nt];
                v = v > 0.f ? v : 0.f;
                epi[(mt * 16 + quad * 4 + r) * 64 + nt * 16 + fr] =
                    (unsigned char)(__builtin_amdgcn_cvt_pk_fp8_f32(v, 0.f, 0, false) & 0xff);
            }
    __asm volatile("s_waitcnt lgkmcnt(0)" ::: "memory");   // in-wave write->read order

    // Sector-complete stores: 16 rows x 4 x 16B segments per instruction.
#pragma unroll
    for (int i = 0; i < 2; ++i) {
        const int r   = i * 16 + (lane >> 2);
        const int seg = lane & 3;
        const uint4 val = *(const uint4*)(epi + r * 64 + seg * 16);
        *(uint4*)(q + (size_t)(row0 + r) * HID_F + wc + seg * 16) = val;
    }
}

// ---------------------------------------------------------------------------
// Kernel 2: aggB[n] = bf16( sum_t w[n,t]*q[nb[n,t]] / sum_t w[n,t] ).
// One wave/node; 4 neighbors per uint4 load (quarter-wave each). 13 iters.
// ---------------------------------------------------------------------------
__global__ __launch_bounds__(256)
void aggk(const unsigned char* __restrict__ q, const int* __restrict__ nb,
          const float* __restrict__ w, unsigned short* __restrict__ aggB) {
    const int node = blockIdx.x * 4 + (threadIdx.x >> 6);
    const int lane = threadIdx.x & 63;

    int   idx_l = 0;
    float w_l   = 0.f;
    if (lane < T_NB) {
        idx_l = nb[(size_t)node * T_NB + lane];
        w_l   = w[(size_t)node * T_NB + lane];
    }
    float sw = w_l;
#pragma unroll
    for (int off = 32; off > 0; off >>= 1)
        sw += __shfl_xor(sw, off, 64);

    const int sub = lane >> 4;       // neighbor slot within group of 4
    const int cg  = lane & 15;       // which 16B column chunk of the row
    float a[16];
#pragma unroll
    for (int j = 0; j < 16; ++j) a[j] = 0.f;

#pragma unroll
    for (int i = 0; i < 13; ++i) {
        const int   t   = 4 * i + sub;              // 0..51; t>=50 has w=0,idx=0
        const int   idx = __shfl(idx_l, t, 64);
        const float wt  = __shfl(w_l, t, 64);
        const uint4 u   = *(const uint4*)(q + (size_t)idx * HID_F + cg * 16);
        v2f p;
        p = __builtin_amdgcn_cvt_pk_f32_fp8(u.x, false); a[0]  += wt * p[0]; a[1]  += wt * p[1];
        p = __builtin_amdgcn_cvt_pk_f32_fp8(u.x, true);  a[2]  += wt * p[0]; a[3]  += wt * p[1];
        p = __builtin_amdgcn_cvt_pk_f32_fp8(u.y, false); a[4]  += wt * p[0]; a[5]  += wt * p[1];
        p = __builtin_amdgcn_cvt_pk_f32_fp8(u.y, true);  a[6]  += wt * p[0]; a[7]  += wt * p[1];
        p = __builtin_amdgcn_cvt_pk_f32_fp8(u.z, false); a[8]  += wt * p[0]; a[9]  += wt * p[1];
        p = __builtin_amdgcn_cvt_pk_f32_fp8(u.z, true);  a[10] += wt * p[0]; a[11] += wt * p[1];
        p = __builtin_amdgcn_cvt_pk_f32_fp8(u.w, false); a[12] += wt * p[0]; a[13] += wt * p[1];
        p = __builtin_amdgcn_cvt_pk_f32_fp8(u.w, true);  a[14] += wt * p[0]; a[15] += wt * p[1];
    }
    // lanes {cg, cg+16, cg+32, cg+48} hold partial sums of the same 16 cols
#pragma unroll
    for (int j = 0; j < 16; ++j) {
        a[j] += __shfl_xor(a[j], 16, 64);
        a[j] += __shfl_xor(a[j], 32, 64);
    }

    if (lane < 16) {
        const float inv = 1.0f / sw;
        bf16x8 v0, v1;
#pragma unroll
        for (int j = 0; j < 8; ++j) {
            v0[j] = (__bf16)(a[j] * inv);
            v1[j] = (__bf16)(a[j + 8] * inv);
        }
        unsigned short* dst = aggB + (size_t)node * HID_F + cg * 16;
        *(bf16x8*)dst       = v0;
        *(bf16x8*)(dst + 8) = v1;
    }
}

// ---------------------------------------------------------------------------
// Kernel 3: out = normalize(relu(concat(h[nodeset], aggB) @ Ww.T + Wb)).
// M=20000 N=256(full) K=512. 64x256 block, 4 waves (wave 64x64, acc 4x4),
// BK=64. kb<4: A = gathered h f32; kb>=4: A = aggB bf16 (no cvt). Fused row
// L2-norm epilogue. (r15-verified, unchanged.)
// ---------------------------------------------------------------------------
__global__ __launch_bounds__(256)
void fgemm(const float* __restrict__ h, const int* __restrict__ nodeset,
           const unsigned short* __restrict__ aggB, const unsigned short* __restrict__ WwB,
           const float* __restrict__ Wb, float* __restrict__ out) {
    __shared__ char smem[50432];
    float* ldsAf = (float*)smem;                             // kb<4: 64r x 16 chunks f32
    unsigned short* ldsAh = (unsigned short*)smem;           // kb>=4: 64r x 8 chunks bf16
    unsigned short* ldsB = (unsigned short*)(smem + 16384);  // 256 n-rows x 8 chunks
    float* ssbuf = (float*)(smem + 49152);                   // [4][64] per-wave row-ss
    float* ssinv = (float*)(smem + 49152 + 1024);            // [64]

    const int tid  = threadIdx.x;
    const int row0 = blockIdx.x * 64;
    const int lane = tid & 63;
    const int wv   = tid >> 6;
    const int wc   = wv << 6;          // wave's 64-col slice of N=256
    const int fr   = lane & 15;
    const int quad = lane >> 4;

    int nsrow[4];
#pragma unroll
    for (int i = 0; i < 4; ++i) {
        const int row = (tid + i * 256) >> 4;
        nsrow[i] = nodeset[min(row0 + row, N_NODES - 1)];
    }
    float bias[4];
#pragma unroll
    for (int nt = 0; nt < 4; ++nt) bias[nt] = Wb[wc + nt * 16 + fr];

    floatx4 acc[4][4];
#pragma unroll
    for (int i = 0; i < 4; ++i)
#pragma unroll
        for (int j = 0; j < 4; ++j)
            acc[i][j] = (floatx4){0.f, 0.f, 0.f, 0.f};

    // ---- kb 0..3: A = h (f32, gathered rows) ----
    for (int kb = 0; kb < 4; ++kb) {
        if (kb) __syncthreads();
#pragma unroll
        for (int i = 0; i < 4; ++i) {
            const int L   = tid + i * 256;
            const int row = L >> 4;
            const int cg  = (L & 15) ^ (row & 15);
            gload16(h + (size_t)nsrow[i] * IN_F + kb * 64 + cg * 4, smem + L * 16);
        }
#pragma unroll
        for (int i = 0; i < 8; ++i) {
            const int L   = tid + i * 256;
            const int row = L >> 3;
            const int cg  = (L & 7) ^ (row & 7);
            gload16(WwB + (size_t)row * KCAT + kb * 64 + cg * 8, smem + 16384 + L * 16);
        }
        __syncthreads();

#pragma unroll
        for (int ks = 0; ks < 2; ++ks) {
            bf16x8 av[4], bv[4];
#pragma unroll
            for (int mt = 0; mt < 4; ++mt) {
                const int row = mt * 16 + fr;
                const int sw  = row & 15;
                const int c0  = ks * 8 + quad * 2;
                const float4 p0 = *(const float4*)(ldsAf + (row * 16 + (c0 ^ sw)) * 4);
                const float4 p1 = *(const float4*)(ldsAf + (row * 16 + ((c0 + 1) ^ sw)) * 4);
                av[mt] = cvt_frag(p0, p1);
            }
#pragma unroll
            for (int nt = 0; nt < 4; ++nt) {
                const int row = wc + nt * 16 + fr;
                const int sw  = row & 7;
                bv[nt] = *reinterpret_cast<const bf16x8*>(ldsB + row * 64 + (((ks * 4 + quad) ^ sw) * 8));
            }
#pragma unroll
            for (int mt = 0; mt < 4; ++mt)
#pragma unroll
                for (int nt = 0; nt < 4; ++nt)
                    acc[mt][nt] = __builtin_amdgcn_mfma_f32_16x16x32_bf16(av[mt], bv[nt], acc[mt][nt], 0, 0, 0);
        }
    }

    // ---- kb 4..7: A = aggB (bf16, B-style stage+read, no cvt) ----
    for (int kb = 4; kb < 8; ++kb) {
        __syncthreads();
#pragma unroll
        for (int i = 0; i < 2; ++i) {
            const int L   = tid + i * 256;
            const int row = L >> 3;
            const int cg  = (L & 7) ^ (row & 7);
            gload16(aggB + (size_t)min(row0 + row, N_NODES - 1) * HID_F + (kb - 4) * 64 + cg * 8,
                    smem + L * 16);
        }
#pragma unroll
        for (int i = 0; i < 8; ++i) {
            const int L   = tid + i * 256;
            const int row = L >> 3;
            const int cg  = (L & 7) ^ (row & 7);
            gload16(WwB + (size_t)row * KCAT + kb * 64 + cg * 8, smem + 16384 + L * 16);
        }
        __syncthreads();

#pragma unroll
        for (int ks = 0; ks < 2; ++ks) {
            bf16x8 av[4], bv[4];
#pragma unroll
            for (int mt = 0; mt < 4; ++mt) {
                const int row = mt * 16 + fr;
                const int sw  = row & 7;
                av[mt] = *reinterpret_cast<const bf16x8*>(ldsAh + row * 64 + (((ks * 4 + quad) ^ sw) * 8));
            }
#pragma unroll
            for (int nt = 0; nt < 4; ++nt) {
                const int row = wc + nt * 16 + fr;
                const int sw  = row & 7;
                bv[nt] = *reinterpret_cast<const bf16x8*>(ldsB + row * 64 + (((ks * 4 + quad) ^ sw) * 8));
            }
#pragma unroll
            for (int mt = 0; mt < 4; ++mt)
#pragma unroll
                for (int nt = 0; nt < 4; ++nt)
                    acc[mt][nt] = __builtin_amdgcn_mfma_f32_16x16x32_bf16(av[mt], bv[nt], acc[mt][nt], 0, 0, 0);
        }
    }

    // --- Fused epilogue: bias+relu, row sum-of-squares, normalize, store.
    // Lane owns rows mt*16 + quad*4 + r, cols wc + nt*16 + fr.
    float ssl[16];
#pragma unroll
    for (int j = 0; j < 16; ++j) ssl[j] = 0.f;
#pragma unroll
    for (int mt = 0; mt < 4; ++mt)
#pragma unroll
        for (int nt = 0; nt < 4; ++nt)
#pragma unroll
            for (int r = 0; r < 4; ++r) {
                float v = acc[mt][nt][r] + bias[nt];
                v = v > 0.f ? v : 0.f;
                acc[mt][nt][r] = v;
                ssl[mt * 4 + r] += v * v;
            }
    // Sum across the 16 fr lanes (xor 1,2,4,8 stays within quad).
#pragma unroll
    for (int j = 0; j < 16; ++j) {
        ssl[j] += __shfl_xor(ssl[j], 1, 64);
        ssl[j] += __shfl_xor(ssl[j], 2, 64);
        ssl[j] += __shfl_xor(ssl[j], 4, 64);
        ssl[j] += __shfl_xor(ssl[j], 8, 64);
    }
    if (fr == 0) {
#pragma unroll
        for (int mt = 0; mt < 4; ++mt)
#pragma unroll
            for (int r = 0; r < 4; ++r)
                ssbuf[wv * 64 + mt * 16 + quad * 4 + r] = ssl[mt * 4 + r];
    }
    __syncthreads();
    if (tid < 64)
        ssinv[tid] = rsqrtf(ssbuf[tid] + ssbuf[64 + tid] + ssbuf[128 + tid] + ssbuf[192 + tid]);
    __syncthreads();

#pragma unroll
    for (int mt = 0; mt < 4; ++mt)
#pragma unroll
        for (int r = 0; r < 4; ++r) {
            const int rl = mt * 16 + quad * 4 + r;
            const int gr = row0 + rl;
            if (gr < N_NODES) {
                const float s = ssinv[rl];
#pragma unroll
                for (int nt = 0; nt < 4; ++nt)
                    out[(size_t)gr * OUT_F + wc + nt * 16 + fr] = acc[mt][nt][r] * s;
            }
        }
}

extern "C" void kernel_launch(void* const* d_in, const int* in_sizes, int n_in,
                              void* d_out, int out_size, void* d_ws, size_t ws_size,
                              hipStream_t stream) {
    const float* h        = (const float*)d_in[0];
    const int*   nodeset  = (const int*)d_in[1];
    const int*   nb_nodes = (const int*)d_in[2];
    const float* nb_w     = (const float*)d_in[3];
    const float* Qw       = (const float*)d_in[4];
    const float* Qb       = (const float*)d_in[5];
    const float* Ww       = (const float*)d_in[6];
    const float* Wb       = (const float*)d_in[7];
    float* out = (float*)d_out;

    unsigned char*  q    = (unsigned char*)d_ws;                          // 25.6 MB
    unsigned short* aggB = (unsigned short*)((char*)d_ws + 25600000);     // 10.24 MB
    unsigned short* QwB  = (unsigned short*)((char*)d_ws + 46080000);     // 128 KB
    unsigned short* WwB  = (unsigned short*)((char*)d_ws + 46211072);     // 256 KB

    wcvt <<<dim3(192),                 256, 0, stream>>>(Qw, Ww, QwB, WwB);
    qgemm<<<dim3(M_TOTAL / 32),        256, 0, stream>>>(h, QwB, Qb, q);
    aggk <<<dim3(N_NODES / 4),         256, 0, stream>>>(q, nb_nodes, nb_w, aggB);
    fgemm<<<dim3((N_NODES + 63) / 64), 256, 0, stream>>>(h, nodeset, aggB, WwB, Wb, out);
}

// Round 11
// 238.276 us; speedup vs baseline: 1.0667x; 1.0667x over previous
//
#include <hip/hip_runtime.h>
#include <hip/hip_bf16.h>

// PinSageConv on MI355X — round 17: EXACT restore of the round-15 best
// (measured 239.3 µs; currently-held v14 kernel measured 254.2).
// qgemm: v8 verbatim — CLOSED. Seven structural variants (v9-v14) all
//   regressed or washed; v14's occupancy experiment (25->36.7%) made it
//   WORSE, falsifying the residency theory. ~61 µs, latency-pinned at
//   ~1.2 TB/s; do not touch.
// aggk v3: bf16 aggB out (traffic-floor bound, ~260MB L3 gather).
// fgemm v3: bf16 kb>=4 A-path + fused row-L2-norm epilogue.
// Workspace: q_fp8[100000][256] @0 (25.6MB) | aggB bf16 @25.6MB (10.24MB)
//            | QwB bf16 @46,080,000 | WwB bf16 @46,211,072.

#define M_TOTAL 100000
#define N_NODES 20000
#define T_NB    50
#define IN_F    256
#define HID_F   256
#define OUT_F   256
#define KCAT    512

typedef __bf16 bf16x8 __attribute__((ext_vector_type(8)));
typedef float  floatx4 __attribute__((ext_vector_type(4)));
typedef float  v2f     __attribute__((ext_vector_type(2)));

__device__ __forceinline__ unsigned short f2bf(float f) {
    unsigned int u = __float_as_uint(f);
    u += 0x7fffu + ((u >> 16) & 1u);          // RTNE
    return (unsigned short)(u >> 16);
}
__device__ __forceinline__ void gload16(const void* g, void* l) {
    __builtin_amdgcn_global_load_lds(
        (const __attribute__((address_space(1))) unsigned int*)g,
        (__attribute__((address_space(3))) unsigned int*)l, 16, 0, 0);
}
__device__ __forceinline__ bf16x8 cvt_frag(float4 a, float4 b) {
    bf16x8 r;
    r[0] = (__bf16)a.x; r[1] = (__bf16)a.y; r[2] = (__bf16)a.z; r[3] = (__bf16)a.w;
    r[4] = (__bf16)b.x; r[5] = (__bf16)b.y; r[6] = (__bf16)b.z; r[7] = (__bf16)b.w;
    return r;
}

// ---------------------------------------------------------------------------
// Kernel 0: convert Qw (65536 f32) and Ww (131072 f32) to bf16.
// ---------------------------------------------------------------------------
__global__ __launch_bounds__(256)
void wcvt(const float* __restrict__ Qw, const float* __restrict__ Ww,
          unsigned short* __restrict__ QwB, unsigned short* __restrict__ WwB) {
    const int e = (blockIdx.x * 256 + threadIdx.x) * 4;
    float4 v;
    unsigned short* dst;
    if (e < 65536) { v = *(const float4*)(Qw + e);           dst = QwB + e; }
    else           { v = *(const float4*)(Ww + (e - 65536)); dst = WwB + (e - 65536); }
    ushort4 s;
    s.x = f2bf(v.x); s.y = f2bf(v.y); s.z = f2bf(v.z); s.w = f2bf(v.w);
    *(ushort4*)dst = s;
}

// ---------------------------------------------------------------------------
// Kernel 1: q = fp8(relu(h @ Qw.T + Qb)).  M=100000 N=256(full) K=256.
// v8 EXACT (harness-verified 60.4/61.8 µs): 64x256 block, 4 waves, A staged
// sync fp32->bf16 into XOR-swizzled LDS, B streamed with 2-deep register
// dbuf, 2 barriers, fp8 epilogue via per-wave LDS quadrant -> uint4 stores.
// ---------------------------------------------------------------------------
__global__ __launch_bounds__(256)
void qgemm(const float* __restrict__ h, const unsigned short* __restrict__ QwB,
           const float* __restrict__ Qb, unsigned char* __restrict__ q) {
    __shared__ unsigned short ldsA[64 * 256];   // 32 KB; reused as fp8 epi tile

    const int tid  = threadIdx.x;
    const int row0 = blockIdx.x * 64;
    const int lane = tid & 63;
    const int wv   = tid >> 6;
    const int wc   = wv << 6;              // wave's 64-col (n) slice
    const int quad = lane >> 4;
    const int fr   = lane & 15;

    // --- Stage A: 64 h-rows fp32 -> bf16 -> swizzled LDS (2048 8-elem chunks).
#pragma unroll
    for (int i = 0; i < 8; ++i) {
        const int C = tid + i * 256;
        const int r = C >> 5;
        const int c = C & 31;
        const int gr = min(row0 + r, M_TOTAL - 1);
        const float4 p0 = *(const float4*)(h + (size_t)gr * IN_F + c * 8);
        const float4 p1 = *(const float4*)(h + (size_t)gr * IN_F + c * 8 + 4);
        *(bf16x8*)(ldsA + r * 256 + ((c ^ (r & 7)) * 8)) = cvt_frag(p0, p1);
    }
    // bias for this lane's 4 n-columns (one per nt), loaded while staging lands
    float bias[4];
#pragma unroll
    for (int nt = 0; nt < 4; ++nt) bias[nt] = Qb[wc + nt * 16 + fr];
    __syncthreads();

    floatx4 acc[4][4];
#pragma unroll
    for (int i = 0; i < 4; ++i)
#pragma unroll
        for (int j = 0; j < 4; ++j)
            acc[i][j] = (floatx4){0.f, 0.f, 0.f, 0.f};

    // B-frag base: row n = wc + nt*16 + fr, k-chunk = kb*4 + quad.
    const unsigned short* bp = QwB + (size_t)(wc + fr) * IN_F + quad * 8;

    bf16x8 bvp[2][4];
#pragma unroll
    for (int nt = 0; nt < 4; ++nt)
        bvp[0][nt] = *(const bf16x8*)(bp + nt * 16 * IN_F);

#pragma unroll
    for (int kb = 0; kb < 8; ++kb) {       // K=256, 32/step — no barriers
        const int cur = kb & 1;
        if (kb < 7) {
#pragma unroll
            for (int nt = 0; nt < 4; ++nt)
                bvp[cur ^ 1][nt] = *(const bf16x8*)(bp + nt * 16 * IN_F + (kb + 1) * 32);
        }
        bf16x8 av[4];
#pragma unroll
        for (int mt = 0; mt < 4; ++mt) {
            const int r = mt * 16 + fr;
            const int c = kb * 4 + quad;
            av[mt] = *(const bf16x8*)(ldsA + r * 256 + ((c ^ (r & 7)) * 8));
        }
#pragma unroll
        for (int mt = 0; mt < 4; ++mt)
#pragma unroll
            for (int nt = 0; nt < 4; ++nt)
                acc[mt][nt] = __builtin_amdgcn_mfma_f32_16x16x32_bf16(av[mt], bvp[cur][nt], acc[mt][nt], 0, 0, 0);
    }

    // --- Epilogue: all waves done reading ldsA, then reuse it as fp8 tile.
    __syncthreads();
    unsigned char* const epi = (unsigned char*)ldsA + wv * 4096;   // 64r x 64c
#pragma unroll
    for (int mt = 0; mt < 4; ++mt)
#pragma unroll
        for (int nt = 0; nt < 4; ++nt)
#pragma unroll
            for (int r = 0; r < 4; ++r) {
                float v = acc[mt][nt][r] + bias[nt];
                v = v > 0.f ? v : 0.f;
                epi[(mt * 16 + quad * 4 + r) * 64 + nt * 16 + fr] =
                    (unsigned char)(__builtin_amdgcn_cvt_pk_fp8_f32(v, 0.f, 0, false) & 0xff);
            }
    __asm volatile("s_waitcnt lgkmcnt(0)" ::: "memory");   // in-wave write->read order

    // Sector-complete stores: 16 rows x 4 x 16B segments per instruction.
#pragma unroll
    for (int i = 0; i < 4; ++i) {
        const int r   = i * 16 + (lane >> 2);
        const int seg = lane & 3;
        const uint4 val = *(const uint4*)(epi + r * 64 + seg * 16);
        const int gr = row0 + r;
        if (gr < M_TOTAL)
            *(uint4*)(q + (size_t)gr * HID_F + wc + seg * 16) = val;
    }
}

// ---------------------------------------------------------------------------
// Kernel 2: aggB[n] = bf16( sum_t w[n,t]*q[nb[n,t]] / sum_t w[n,t] ).
// One wave/node; 4 neighbors per uint4 load (quarter-wave each). 13 iters.
// Store: 16 lanes x 32B bf16 = 512B contiguous row (RTNE via (__bf16) cast,
// identical values to fgemm's old f32->bf16 fragment conversion).
// ---------------------------------------------------------------------------
__global__ __launch_bounds__(256)
void aggk(const unsigned char* __restrict__ q, const int* __restrict__ nb,
          const float* __restrict__ w, unsigned short* __restrict__ aggB) {
    const int node = blockIdx.x * 4 + (threadIdx.x >> 6);
    const int lane = threadIdx.x & 63;

    int   idx_l = 0;
    float w_l   = 0.f;
    if (lane < T_NB) {
        idx_l = nb[(size_t)node * T_NB + lane];
        w_l   = w[(size_t)node * T_NB + lane];
    }
    float sw = w_l;
#pragma unroll
    for (int off = 32; off > 0; off >>= 1)
        sw += __shfl_xor(sw, off, 64);

    const int sub = lane >> 4;       // neighbor slot within group of 4
    const int cg  = lane & 15;       // which 16B column chunk of the row
    float a[16];
#pragma unroll
    for (int j = 0; j < 16; ++j) a[j] = 0.f;

#pragma unroll
    for (int i = 0; i < 13; ++i) {
        const int   t   = 4 * i + sub;              // 0..51; t>=50 has w=0,idx=0
        const int   idx = __shfl(idx_l, t, 64);
        const float wt  = __shfl(w_l, t, 64);
        const uint4 u   = *(const uint4*)(q + (size_t)idx * HID_F + cg * 16);
        v2f p;
        p = __builtin_amdgcn_cvt_pk_f32_fp8(u.x, false); a[0]  += wt * p[0]; a[1]  += wt * p[1];
        p = __builtin_amdgcn_cvt_pk_f32_fp8(u.x, true);  a[2]  += wt * p[0]; a[3]  += wt * p[1];
        p = __builtin_amdgcn_cvt_pk_f32_fp8(u.y, false); a[4]  += wt * p[0]; a[5]  += wt * p[1];
        p = __builtin_amdgcn_cvt_pk_f32_fp8(u.y, true);  a[6]  += wt * p[0]; a[7]  += wt * p[1];
        p = __builtin_amdgcn_cvt_pk_f32_fp8(u.z, false); a[8]  += wt * p[0]; a[9]  += wt * p[1];
        p = __builtin_amdgcn_cvt_pk_f32_fp8(u.z, true);  a[10] += wt * p[0]; a[11] += wt * p[1];
        p = __builtin_amdgcn_cvt_pk_f32_fp8(u.w, false); a[12] += wt * p[0]; a[13] += wt * p[1];
        p = __builtin_amdgcn_cvt_pk_f32_fp8(u.w, true);  a[14] += wt * p[0]; a[15] += wt * p[1];
    }
    // lanes {cg, cg+16, cg+32, cg+48} hold partial sums of the same 16 cols
#pragma unroll
    for (int j = 0; j < 16; ++j) {
        a[j] += __shfl_xor(a[j], 16, 64);
        a[j] += __shfl_xor(a[j], 32, 64);
    }

    if (lane < 16) {
        const float inv = 1.0f / sw;
        bf16x8 v0, v1;
#pragma unroll
        for (int j = 0; j < 8; ++j) {
            v0[j] = (__bf16)(a[j] * inv);
            v1[j] = (__bf16)(a[j + 8] * inv);
        }
        unsigned short* dst = aggB + (size_t)node * HID_F + cg * 16;
        *(bf16x8*)dst       = v0;
        *(bf16x8*)(dst + 8) = v1;
    }
}

// ---------------------------------------------------------------------------
// Kernel 3: out = normalize(relu(concat(h[nodeset], aggB) @ Ww.T + Wb)).
// M=20000 N=256(full) K=512. 64x256 block, 4 waves (wave 64x64, acc 4x4),
// BK=64. kb<4: A = gathered h f32 (16KB stage, cvt at fragment build).
// kb>=4: A = aggB bf16 (8KB stage, B-style chunk swizzle (L&7)^(row&7),
// direct bf16x8 reads — no cvt). B: WwB bf16 (32KB stage). Fused row
// L2-norm epilogue (r13-verified).
// ---------------------------------------------------------------------------
__global__ __launch_bounds__(256)
void fgemm(const float* __restrict__ h, const int* __restrict__ nodeset,
           const unsigned short* __restrict__ aggB, const unsigned short* __restrict__ WwB,
           const float* __restrict__ Wb, float* __restrict__ out) {
    __shared__ char smem[50432];
    float* ldsAf = (float*)smem;                             // kb<4: 64r x 16 chunks f32
    unsigned short* ldsAh = (unsigned short*)smem;           // kb>=4: 64r x 8 chunks bf16
    unsigned short* ldsB = (unsigned short*)(smem + 16384);  // 256 n-rows x 8 chunks
    float* ssbuf = (float*)(smem + 49152);                   // [4][64] per-wave row-ss
    float* ssinv = (float*)(smem + 49152 + 1024);            // [64]

    const int tid  = threadIdx.x;
    const int row0 = blockIdx.x * 64;
    const int lane = tid & 63;
    const int wv   = tid >> 6;
    const int wc   = wv << 6;          // wave's 64-col slice of N=256
    const int fr   = lane & 15;
    const int quad = lane >> 4;

    int nsrow[4];
#pragma unroll
    for (int i = 0; i < 4; ++i) {
        const int row = (tid + i * 256) >> 4;
        nsrow[i] = nodeset[min(row0 + row, N_NODES - 1)];
    }
    float bias[4];
#pragma unroll
    for (int nt = 0; nt < 4; ++nt) bias[nt] = Wb[wc + nt * 16 + fr];

    floatx4 acc[4][4];
#pragma unroll
    for (int i = 0; i < 4; ++i)
#pragma unroll
        for (int j = 0; j < 4; ++j)
            acc[i][j] = (floatx4){0.f, 0.f, 0.f, 0.f};

    // ---- kb 0..3: A = h (f32, gathered rows) ----
    for (int kb = 0; kb < 4; ++kb) {
        if (kb) __syncthreads();
#pragma unroll
        for (int i = 0; i < 4; ++i) {
            const int L   = tid + i * 256;
            const int row = L >> 4;
            const int cg  = (L & 15) ^ (row & 15);
            gload16(h + (size_t)nsrow[i] * IN_F + kb * 64 + cg * 4, smem + L * 16);
        }
#pragma unroll
        for (int i = 0; i < 8; ++i) {
            const int L   = tid + i * 256;
            const int row = L >> 3;
            const int cg  = (L & 7) ^ (row & 7);
            gload16(WwB + (size_t)row * KCAT + kb * 64 + cg * 8, smem + 16384 + L * 16);
        }
        __syncthreads();

#pragma unroll
        for (int ks = 0; ks < 2; ++ks) {
            bf16x8 av[4], bv[4];
#pragma unroll
            for (int mt = 0; mt < 4; ++mt) {
                const int row = mt * 16 + fr;
                const int sw  = row & 15;
                const int c0  = ks * 8 + quad * 2;
                const float4 p0 = *(const float4*)(ldsAf + (row * 16 + (c0 ^ sw)) * 4);
                const float4 p1 = *(const float4*)(ldsAf + (row * 16 + ((c0 + 1) ^ sw)) * 4);
                av[mt] = cvt_frag(p0, p1);
            }
#pragma unroll
            for (int nt = 0; nt < 4; ++nt) {
                const int row = wc + nt * 16 + fr;
                const int sw  = row & 7;
                bv[nt] = *reinterpret_cast<const bf16x8*>(ldsB + row * 64 + (((ks * 4 + quad) ^ sw) * 8));
            }
#pragma unroll
            for (int mt = 0; mt < 4; ++mt)
#pragma unroll
                for (int nt = 0; nt < 4; ++nt)
                    acc[mt][nt] = __builtin_amdgcn_mfma_f32_16x16x32_bf16(av[mt], bv[nt], acc[mt][nt], 0, 0, 0);
        }
    }

    // ---- kb 4..7: A = aggB (bf16, B-style stage+read, no cvt) ----
    for (int kb = 4; kb < 8; ++kb) {
        __syncthreads();
#pragma unroll
        for (int i = 0; i < 2; ++i) {
            const int L   = tid + i * 256;
            const int row = L >> 3;
            const int cg  = (L & 7) ^ (row & 7);
            gload16(aggB + (size_t)min(row0 + row, N_NODES - 1) * HID_F + (kb - 4) * 64 + cg * 8,
                    smem + L * 16);
        }
#pragma unroll
        for (int i = 0; i < 8; ++i) {
            const int L   = tid + i * 256;
            const int row = L >> 3;
            const int cg  = (L & 7) ^ (row & 7);
            gload16(WwB + (size_t)row * KCAT + kb * 64 + cg * 8, smem + 16384 + L * 16);
        }
        __syncthreads();

#pragma unroll
        for (int ks = 0; ks < 2; ++ks) {
            bf16x8 av[4], bv[4];
#pragma unroll
            for (int mt = 0; mt < 4; ++mt) {
                const int row = mt * 16 + fr;
                const int sw  = row & 7;
                av[mt] = *reinterpret_cast<const bf16x8*>(ldsAh + row * 64 + (((ks * 4 + quad) ^ sw) * 8));
            }
#pragma unroll
            for (int nt = 0; nt < 4; ++nt) {
                const int row = wc + nt * 16 + fr;
                const int sw  = row & 7;
                bv[nt] = *reinterpret_cast<const bf16x8*>(ldsB + row * 64 + (((ks * 4 + quad) ^ sw) * 8));
            }
#pragma unroll
            for (int mt = 0; mt < 4; ++mt)
#pragma unroll
                for (int nt = 0; nt < 4; ++nt)
                    acc[mt][nt] = __builtin_amdgcn_mfma_f32_16x16x32_bf16(av[mt], bv[nt], acc[mt][nt], 0, 0, 0);
        }
    }

    // --- Fused epilogue: bias+relu, row sum-of-squares, normalize, store.
    // Lane owns rows mt*16 + quad*4 + r, cols wc + nt*16 + fr.
    float ssl[16];
#pragma unroll
    for (int j = 0; j < 16; ++j) ssl[j] = 0.f;
#pragma unroll
    for (int mt = 0; mt < 4; ++mt)
#pragma unroll
        for (int nt = 0; nt < 4; ++nt)
#pragma unroll
            for (int r = 0; r < 4; ++r) {
                float v = acc[mt][nt][r] + bias[nt];
                v = v > 0.f ? v : 0.f;
                acc[mt][nt][r] = v;
                ssl[mt * 4 + r] += v * v;
            }
    // Sum across the 16 fr lanes (xor 1,2,4,8 stays within quad).
#pragma unroll
    for (int j = 0; j < 16; ++j) {
        ssl[j] += __shfl_xor(ssl[j], 1, 64);
        ssl[j] += __shfl_xor(ssl[j], 2, 64);
        ssl[j] += __shfl_xor(ssl[j], 4, 64);
        ssl[j] += __shfl_xor(ssl[j], 8, 64);
    }
    if (fr == 0) {
#pragma unroll
        for (int mt = 0; mt < 4; ++mt)
#pragma unroll
            for (int r = 0; r < 4; ++r)
                ssbuf[wv * 64 + mt * 16 + quad * 4 + r] = ssl[mt * 4 + r];
    }
    __syncthreads();
    if (tid < 64)
        ssinv[tid] = rsqrtf(ssbuf[tid] + ssbuf[64 + tid] + ssbuf[128 + tid] + ssbuf[192 + tid]);
    __syncthreads();

#pragma unroll
    for (int mt = 0; mt < 4; ++mt)
#pragma unroll
        for (int r = 0; r < 4; ++r) {
            const int rl = mt * 16 + quad * 4 + r;
            const int gr = row0 + rl;
            if (gr < N_NODES) {
                const float s = ssinv[rl];
#pragma unroll
                for (int nt = 0; nt < 4; ++nt)
                    out[(size_t)gr * OUT_F + wc + nt * 16 + fr] = acc[mt][nt][r] * s;
            }
        }
}

extern "C" void kernel_launch(void* const* d_in, const int* in_sizes, int n_in,
                              void* d_out, int out_size, void* d_ws, size_t ws_size,
                              hipStream_t stream) {
    const float* h        = (const float*)d_in[0];
    const int*   nodeset  = (const int*)d_in[1];
    const int*   nb_nodes = (const int*)d_in[2];
    const float* nb_w     = (const float*)d_in[3];
    const float* Qw       = (const float*)d_in[4];
    const float* Qb       = (const float*)d_in[5];
    const float* Ww       = (const float*)d_in[6];
    const float* Wb       = (const float*)d_in[7];
    float* out = (float*)d_out;

    unsigned char*  q    = (unsigned char*)d_ws;                          // 25.6 MB
    unsigned short* aggB = (unsigned short*)((char*)d_ws + 25600000);     // 10.24 MB
    unsigned short* QwB  = (unsigned short*)((char*)d_ws + 46080000);     // 128 KB
    unsigned short* WwB  = (unsigned short*)((char*)d_ws + 46211072);     // 256 KB

    wcvt <<<dim3(192),                 256, 0, stream>>>(Qw, Ww, QwB, WwB);
    qgemm<<<dim3((M_TOTAL + 63) / 64), 256, 0, stream>>>(h, QwB, Qb, q);
    aggk <<<dim3(N_NODES / 4),         256, 0, stream>>>(q, nb_nodes, nb_w, aggB);
    fgemm<<<dim3((N_NODES + 63) / 64), 256, 0, stream>>>(h, nodeset, aggB, WwB, Wb, out);
}